// Round 2
// baseline (207.569 us; speedup 1.0000x reference)
//
#include <hip/hip_runtime.h>
#include <math.h>

// Problem constants
#define BB 4
#define CIN 64
#define COUT 64
#define HH 128
#define WW 128
#define HW (HH*WW)

typedef __attribute__((ext_vector_type(8))) short short8;   // 8 bf16 = 4 VGPRs
typedef __attribute__((ext_vector_type(4))) float f32x4;
typedef __attribute__((ext_vector_type(4))) unsigned int uint4v;

static __device__ __forceinline__ unsigned short f2bf(float f) {
    unsigned int u = __builtin_bit_cast(unsigned int, f);
    u += 0x7fffu + ((u >> 16) & 1u);          // round-to-nearest-even
    return (unsigned short)(u >> 16);
}
static __device__ __forceinline__ float bf2f(unsigned short h) {
    unsigned int u = ((unsigned int)h) << 16;
    return __builtin_bit_cast(float, u);
}

// ---------------------------------------------------------------------------
// K1: wkpack (80 blocks) + bias2 (1 block).  Tiny; everything else moved out.
// ---------------------------------------------------------------------------
__global__ __launch_bounds__(256) void prep_kernel(
        const float* __restrict__ com_w, const float* __restrict__ c2w,
        const float* __restrict__ bias,
        unsigned short* __restrict__ wk2, float* __restrict__ bias2) {
    int id = blockIdx.x, tid = threadIdx.x;
    if (id < 80) {
        int i = id*256 + tid;               // < 20480
        int k = i & 31, oc = (i >> 5) & 31;
        int cc5 = i >> 10;                  // cg*5 + chunk
        int cg = cc5 / 5, ch = cc5 % 5;
        int tap = ch*2 + (k >> 4);
        int c = cg*16 + (k & 15);
        float v = 0.f;
        if (tap < 9 && oc < 27) v = com_w[((size_t)oc*64 + c)*9 + tap];
        wk2[i] = f2bf(v);
    } else if (tid < COUT) {
        float s2 = 0.f;
        for (int o = 0; o < COUT; ++o) s2 += c2w[tid*COUT + o] * bias[o];
        bias2[tid] = s2;
    }
}

// ---------------------------------------------------------------------------
// channel-last bf16 transpose of one (b, 64-px strip): src[b][c][px]->dst[b][px][c]
// ---------------------------------------------------------------------------
static __device__ __forceinline__ void transpose_body(
        const float* __restrict__ srcb, unsigned short* __restrict__ dstb,
        int tb, int tid, float* lt /* 64*65 floats */) {
    int b = tb >> 8;
    int px0 = (tb & 255) * 64;
    const float* src = srcb + (size_t)b*CIN*HW + px0;
    for (int i = tid; i < 4096; i += 256) {
        int c = i >> 6, px = i & 63;
        lt[c*65 + px] = src[(size_t)c*HW + px];
    }
    __syncthreads();
    int q = tid & 3, px = tid >> 2;
    unsigned short* dst = dstb + ((size_t)b*HW + px0 + px)*64 + q*16;
    #pragma unroll
    for (int s = 0; s < 2; ++s) {
        short8 pk;
        #pragma unroll
        for (int j = 0; j < 8; ++j)
            pk[j] = (short)f2bf(lt[(q*16 + s*8 + j)*65 + px]);
        *(short8*)(dst + s*8) = pk;
    }
}

// ---------------------------------------------------------------------------
// w2 with INLINE fvec (wave-reduced): W2b[b][p][o2][c] bf16 (MFMA A layout)
// ---------------------------------------------------------------------------
static __device__ __forceinline__ void w2_body(
        int wid, int tid, const float* __restrict__ weight,
        const float* __restrict__ c2w, const float* __restrict__ c1w,
        const float* __restrict__ fea,
        unsigned short* __restrict__ w2b, float* c2s, float* wcol) {
    int o2 = tid & 63, ci = tid >> 6;
    int lane = tid & 63;
    int bp = wid >> 4;
    int c_base = (wid & 15)*4;
    int p = bp % 9, b = bp / 9;
    int c = c_base + ci;

    // inline fvec[b][c] for this wave's c: 4 MAC/lane + wave reduce
    float part = 0.f;
    #pragma unroll
    for (int s = 0; s < 4; ++s)
        part += c1w[c*(4*CIN) + lane + s*64] * fea[b*(4*CIN) + lane + s*64];
    #pragma unroll
    for (int off = 32; off; off >>= 1) part += __shfl_down(part, off);
    float fv = __shfl(part, 0);

    for (int idx = tid; idx < 4096; idx += 256) {
        int o2r = idx >> 6, oc = idx & 63;
        c2s[oc*65 + o2r] = c2w[idx];
    }
    {
        int o = tid & 63, cw = tid >> 6;
        wcol[cw*64 + o] = weight[(o*CIN + (c_base + cw))*9 + p];
    }
    __syncthreads();
    float s = 0.f;
    #pragma unroll 8
    for (int o = 0; o < COUT; ++o) s += c2s[o*65 + o2] * wcol[ci*64 + o];
    w2b[(size_t)bp*4096 + o2*64 + c] = f2bf(s * fv);
}

// ---------------------------------------------------------------------------
// conv via LDS im2col tile from fp32 inter (round-7-proven)
// ---------------------------------------------------------------------------
static __device__ __forceinline__ void conv_lds_body(
        int id, int tid, const float* __restrict__ inter,
        const unsigned short* __restrict__ wk2, const float* __restrict__ com_b,
        float* __restrict__ om, float* smemf) {
    unsigned short* til = (unsigned short*)smemf;   // [325][24]
    int bz = id >> 6;
    int b = bz >> 1, mh = bz & 1;
    int by = (id >> 3) & 7, bx = id & 7;
    int x0 = bx*16, y0 = by*16;
    int lane = tid & 63, wv = tid >> 6;
    int nn = lane & 15, qq = lane >> 4;

    f32x4 acc[4];
    #pragma unroll
    for (int nt = 0; nt < 4; ++nt)
        #pragma unroll
        for (int j = 0; j < 4; ++j) acc[nt][j] = 0.f;

    for (int cg = 0; cg < 4; ++cg) {
        __syncthreads();
        const float* I = inter + ((size_t)(b*CIN + cg*16))*HW;
        for (int i = tid; i < 16*324; i += 256) {
            int cl = i / 324, px = i % 324;
            int r = px / 18, cc = px % 18;
            int gy = y0 + r - 1, gx = x0 + cc - 1;
            float v = 0.f;
            if (gy >= 0 && gy < HH && gx >= 0 && gx < WW)
                v = I[(size_t)cl*HW + gy*WW + gx];
            til[px*24 + cl] = f2bf(v);
        }
        if (tid < 24) til[324*24 + tid] = 0;
        __syncthreads();

        short8 afr[5];
        #pragma unroll
        for (int ch = 0; ch < 5; ++ch)
            afr[ch] = *(const short8*)(wk2 +
                (((size_t)(cg*5 + ch)*32 + mh*16 + nn)*32 + qq*8));
        #pragma unroll
        for (int nt = 0; nt < 4; ++nt) {
            int row = wv*4 + nt;
            #pragma unroll
            for (int ch = 0; ch < 5; ++ch) {
                int tap = ch*2 + (qq >> 1);
                int px_idx;
                if (tap > 8) px_idx = 324;
                else {
                    int ky = tap/3, kx = tap%3;
                    px_idx = (row + ky)*18 + (nn + kx);
                }
                short8 bfr = *(const short8*)(til + px_idx*24 + (qq&1)*8);
                acc[nt] = __builtin_amdgcn_mfma_f32_16x16x32_bf16(
                              afr[ch], bfr, acc[nt], 0, 0, 0);
            }
        }
    }

    float* op = om + (size_t)b*27*HW;
    #pragma unroll
    for (int nt = 0; nt < 4; ++nt) {
        int pix = (y0 + wv*4 + nt)*WW + x0 + nn;
        #pragma unroll
        for (int j = 0; j < 4; ++j) {
            int oc = mh*16 + qq*4 + j;
            if (oc < 27)
                op[(size_t)oc*HW + pix] = acc[nt][j] + com_b[oc];
        }
    }
}

// ---------------------------------------------------------------------------
// K2: conv (512) + w2 (576) + fT transpose (1024) = 2112 blocks
// ---------------------------------------------------------------------------
__global__ __launch_bounds__(256) void main2_kernel(
        const float* __restrict__ input_feat,
        const float* __restrict__ inter,
        const unsigned short* __restrict__ wk2,
        const float* __restrict__ com_b,
        const float* __restrict__ weight,
        const float* __restrict__ c2w,
        const float* __restrict__ c1w,
        const float* __restrict__ fea,
        float* __restrict__ om, unsigned short* __restrict__ w2b,
        unsigned short* __restrict__ fT) {
    __shared__ __align__(16) float smem[4416];
    int id = blockIdx.x, tid = threadIdx.x;
    if (id < 512)        conv_lds_body(id, tid, inter, wk2, com_b, om, smem);
    else if (id < 1088)  w2_body(id - 512, tid, weight, c2w, c1w, fea, w2b,
                                 smem, smem + 64*65);
    else                 transpose_body(input_feat, fT, id - 1088, tid, smem);
}

// ---------------------------------------------------------------------------
// K3: main DCN GEMM, bf16 MFMA, split-K across wave pairs.
// v2 (locality theory), resubmitted after infra failure:
//  * 1D grid + XCD batch-binding swizzle: xcd = blk&7, b = xcd>>1.  Each XCD's
//    working set (fT[b] 2MB + om[b] 1.8MB + w2b[b] 72KB) now fits its 4MB L2.
//  * A-frags (w2b) LDS-staged per tap, double-buffered, XOR-swizzled
//    (byte ^= (row&7)<<4): kills the 4 scattered global A-loads/wave/tap and
//    the 2x strip duplication; stage loads issued early, ds_write late (T14).
//  * __launch_bounds__(256,8) pins VGPR<=64 to keep 32 waves/CU.
// ---------------------------------------------------------------------------
__global__ __launch_bounds__(256, 8) void dcn_main_kernel(
        const unsigned short* __restrict__ fT,
        const unsigned short* __restrict__ w2b,
        const float* __restrict__ bias2,
        const float* __restrict__ om,
        float* __restrict__ out) {
    __shared__ __align__(16) unsigned short aT[2][4096];   // 2 x 8KB A-tile
    int id = blockIdx.x;                 // 0..2047
    int xcd = id & 7;                    // round-robin XCD assignment
    int jj  = id >> 3;                   // 0..255 within this XCD
    int b   = xcd >> 1;                  // 2 XCDs per batch -> per-XCD L2 fit
    int y   = jj & 127;
    int xq  = ((xcd & 1) << 1) | (jj >> 7);   // 0..3 (bijective with old grid.x)

    int t = threadIdx.x;
    int lane = t & 63, wv = t >> 6;
    int strip = wv >> 1, kh = wv & 1;
    int nn = lane & 15, qq = lane >> 4;
    int px0 = xq*32 + strip*16;
    int x = px0 + nn;
    int pix = y*WW + x;
    const unsigned short* Fb = fT + (size_t)b*HW*64;
    const float* omb = om + (size_t)b*27*HW;
    const unsigned short* w2src = w2b + (size_t)(b*9)*4096;
    int co = kh*32 + qq*8;

    // staging (write) addressing: thread t covers elements [t*16, t*16+16)
    int sb0 = t*32;                       // byte offset of chunk0
    int ssw = ((t >> 2) & 7) << 4;        // row = byte>>7 = t>>2
    char* aTc0 = (char*)aT[0];
    char* aTc1 = (char*)aT[1];
    // afr (read) addressing: elem byte = (mt*16+nn)*128 + kh*64 + qq*16,
    // swizzle row&7 = nn&7  -> max 2-way bank aliasing (free)
    int rsw   = (nn & 7) << 4;
    int rbase = kh*64 + qq*16;

    f32x4 acc[4];
    #pragma unroll
    for (int mt = 0; mt < 4; ++mt)
        #pragma unroll
        for (int j = 0; j < 4; ++j)
            acc[mt][j] = kh ? bias2[mt*16 + qq*4 + j] : 0.f;

    // prologue: stage tap 0 A-tile
    {
        short8 s0 = *(const short8*)(w2src + t*16);
        short8 s1 = *(const short8*)(w2src + t*16 + 8);
        *(short8*)(aTc0 + (sb0 ^ ssw)) = s0;
        *(short8*)(aTc0 + ((sb0 + 16) ^ ssw)) = s1;
    }

    float omy = omb[pix];
    float omx = omb[(size_t)HW + pix];
    float omm = omb[(size_t)18*HW + pix];
    __syncthreads();

    #pragma unroll
    for (int p = 0; p < 9; ++p) {
        char* bufR = (p & 1) ? aTc1 : aTc0;
        char* bufW = (p & 1) ? aTc0 : aTc1;

        // issue next tap's stage loads early (hide under gather wait)
        short8 s0, s1;
        if (p < 8) {
            const unsigned short* src = w2src + (size_t)(p + 1)*4096;
            s0 = *(const short8*)(src + t*16);
            s1 = *(const short8*)(src + t*16 + 8);
        }

        // A-frags for my K-half from LDS (swizzled, conflict-free)
        short8 afr[4];
        #pragma unroll
        for (int mt = 0; mt < 4; ++mt)
            afr[mt] = *(const short8*)(bufR +
                          (((mt*16 + nn)*128 + rbase) ^ rsw));

        // bilinear corner weights for my pixel
        float mv = 1.f / (1.f + expf(-omm));
        float ysv = (float)(y - 1 + p/3) + omy;
        float xsv = (float)(x - 1 + p%3) + omx;
        float y0f = floorf(ysv), x0f = floorf(xsv);
        float ly = ysv - y0f, lx = xsv - x0f;
        int y0 = (int)y0f, x0i = (int)x0f;
        int y1 = y0 + 1, x1 = x0i + 1;
        float vy0 = (y0 >= 0 && y0 < HH) ? 1.f : 0.f;
        float vy1 = (y1 >= 0 && y1 < HH) ? 1.f : 0.f;
        float vx0 = (x0i >= 0 && x0i < WW) ? 1.f : 0.f;
        float vx1 = (x1 >= 0 && x1 < WW) ? 1.f : 0.f;
        float w00 = (1.f-ly)*(1.f-lx)*mv * vy0*vx0;
        float w01 = (1.f-ly)*lx      *mv * vy0*vx1;
        float w10 = ly      *(1.f-lx)*mv * vy1*vx0;
        float w11 = ly      *lx      *mv * vy1*vx1;
        int y0c = min(max(y0,0),HH-1), y1c = min(max(y1,0),HH-1);
        int x0c = min(max(x0i,0),WW-1), x1c = min(max(x1,0),WW-1);
        int i00 = y0c*WW + x0c, i01 = y0c*WW + x1c;
        int i10 = y1c*WW + x0c, i11 = y1c*WW + x1c;

        // prefetch next p's om
        if (p < 8) {
            omy = omb[(size_t)(2*p+2)*HW + pix];
            omx = omb[(size_t)(2*p+3)*HW + pix];
            omm = omb[(size_t)(19+p )*HW + pix];
        }

        // gather my 8 channels' 4 corners (16B each, channel-contiguous)
        short8 c00 = *(const short8*)(Fb + (size_t)i00*64 + co);
        short8 c01 = *(const short8*)(Fb + (size_t)i01*64 + co);
        short8 c10 = *(const short8*)(Fb + (size_t)i10*64 + co);
        short8 c11 = *(const short8*)(Fb + (size_t)i11*64 + co);

        // write next tap's A-tile (stage latency overlaps gather wait)
        if (p < 8) {
            *(short8*)(bufW + (sb0 ^ ssw)) = s0;
            *(short8*)(bufW + ((sb0 + 16) ^ ssw)) = s1;
        }

        // pack
        unsigned int pw[4];
        #pragma unroll
        for (int jp = 0; jp < 4; ++jp) {
            float v0 = w00*bf2f((unsigned short)c00[2*jp])
                     + w01*bf2f((unsigned short)c01[2*jp])
                     + w10*bf2f((unsigned short)c10[2*jp])
                     + w11*bf2f((unsigned short)c11[2*jp]);
            float v1 = w00*bf2f((unsigned short)c00[2*jp+1])
                     + w01*bf2f((unsigned short)c01[2*jp+1])
                     + w10*bf2f((unsigned short)c10[2*jp+1])
                     + w11*bf2f((unsigned short)c11[2*jp+1]);
            pw[jp] = (unsigned int)f2bf(v0) | ((unsigned int)f2bf(v1) << 16);
        }
        uint4v u4 = {pw[0], pw[1], pw[2], pw[3]};
        short8 bfr = __builtin_bit_cast(short8, u4);

        // MFMA (my K-half only)
        #pragma unroll
        for (int mt = 0; mt < 4; ++mt)
            acc[mt] = __builtin_amdgcn_mfma_f32_16x16x32_bf16(
                          afr[mt], bfr, acc[mt], 0, 0, 0);

        __syncthreads();
    }

    // combine wave-pair partials via LDS (reuse aT[1]: 8KB, free after loop;
    // tap 8 read buffer was aT[0])
    float* red = (float*)aTc1;
    if (kh == 0) {
        #pragma unroll
        for (int mt = 0; mt < 4; ++mt)
            #pragma unroll
            for (int j = 0; j < 4; ++j)
                red[(mt*4 + j)*128 + strip*64 + lane] = acc[mt][j];
    }
    __syncthreads();
    if (kh == 1) {
        float* outp = out + (size_t)b*COUT*HW + (size_t)y*WW + px0 + nn;
        #pragma unroll
        for (int mt = 0; mt < 4; ++mt)
            #pragma unroll
            for (int j = 0; j < 4; ++j)
                outp[(size_t)(mt*16 + qq*4 + j)*HW] =
                    acc[mt][j] + red[(mt*4 + j)*128 + strip*64 + lane];
    }
}

// ---------------------------------------------------------------------------
extern "C" void kernel_launch(void* const* d_in, const int* in_sizes, int n_in,
                              void* d_out, int out_size, void* d_ws, size_t ws_size,
                              hipStream_t stream) {
    const float* input_feat = (const float*)d_in[0];
    const float* inter      = (const float*)d_in[1];
    const float* fea        = (const float*)d_in[2];
    const float* weight     = (const float*)d_in[3];
    const float* bias       = (const float*)d_in[4];
    const float* com_w      = (const float*)d_in[5];
    const float* com_b      = (const float*)d_in[6];
    const float* c1w        = (const float*)d_in[7];
    const float* c2w        = (const float*)d_in[8];
    float* out = (float*)d_out;

    float* ws    = (float*)d_ws;
    float* bias2 = ws + 256;                               // 64 (in pad area)
    unsigned short* w2b = (unsigned short*)(ws + 512);     // 147456 us
    float* om    = ws + 512 + 73728;                       // 1769472 f
    unsigned short* wk2 = (unsigned short*)(om + 1769472); // 20480 us
    unsigned short* fT  = wk2 + 20480;                     // 4194304 us

    prep_kernel<<<81, 256, 0, stream>>>(com_w, c2w, bias, wk2, bias2);
    main2_kernel<<<2112, 256, 0, stream>>>(input_feat, inter, wk2, com_b,
                                           weight, c2w, c1w, fea, om, w2b, fT);
    dcn_main_kernel<<<2048, 256, 0, stream>>>(fT, w2b, bias2, om, out);
}

// Round 3
// 170.407 us; speedup vs baseline: 1.2181x; 1.2181x over previous
//
#include <hip/hip_runtime.h>
#include <math.h>

// Problem constants
#define BB 4
#define CIN 64
#define COUT 64
#define HH 128
#define WW 128
#define HW (HH*WW)

typedef __attribute__((ext_vector_type(8))) short short8;   // 8 bf16 = 4 VGPRs
typedef __attribute__((ext_vector_type(4))) float f32x4;
typedef __attribute__((ext_vector_type(4))) unsigned int uint4v;

static __device__ __forceinline__ unsigned short f2bf(float f) {
    unsigned int u = __builtin_bit_cast(unsigned int, f);
    u += 0x7fffu + ((u >> 16) & 1u);          // round-to-nearest-even
    return (unsigned short)(u >> 16);
}
static __device__ __forceinline__ float bf2f(unsigned short h) {
    unsigned int u = ((unsigned int)h) << 16;
    return __builtin_bit_cast(float, u);
}

// ---------------------------------------------------------------------------
// K1: wkpack (80 blocks) + bias2 (1 block).  Tiny; everything else moved out.
// ---------------------------------------------------------------------------
__global__ __launch_bounds__(256) void prep_kernel(
        const float* __restrict__ com_w, const float* __restrict__ c2w,
        const float* __restrict__ bias,
        unsigned short* __restrict__ wk2, float* __restrict__ bias2) {
    int id = blockIdx.x, tid = threadIdx.x;
    if (id < 80) {
        int i = id*256 + tid;               // < 20480
        int k = i & 31, oc = (i >> 5) & 31;
        int cc5 = i >> 10;                  // cg*5 + chunk
        int cg = cc5 / 5, ch = cc5 % 5;
        int tap = ch*2 + (k >> 4);
        int c = cg*16 + (k & 15);
        float v = 0.f;
        if (tap < 9 && oc < 27) v = com_w[((size_t)oc*64 + c)*9 + tap];
        wk2[i] = f2bf(v);
    } else if (tid < COUT) {
        float s2 = 0.f;
        for (int o = 0; o < COUT; ++o) s2 += c2w[tid*COUT + o] * bias[o];
        bias2[tid] = s2;
    }
}

// ---------------------------------------------------------------------------
// channel-last bf16 transpose of one (b, 64-px strip): src[b][c][px]->dst[b][px][c]
// ---------------------------------------------------------------------------
static __device__ __forceinline__ void transpose_body(
        const float* __restrict__ srcb, unsigned short* __restrict__ dstb,
        int tb, int tid, float* lt /* 64*65 floats */) {
    int b = tb >> 8;
    int px0 = (tb & 255) * 64;
    const float* src = srcb + (size_t)b*CIN*HW + px0;
    for (int i = tid; i < 4096; i += 256) {
        int c = i >> 6, px = i & 63;
        lt[c*65 + px] = src[(size_t)c*HW + px];
    }
    __syncthreads();
    int q = tid & 3, px = tid >> 2;
    unsigned short* dst = dstb + ((size_t)b*HW + px0 + px)*64 + q*16;
    #pragma unroll
    for (int s = 0; s < 2; ++s) {
        short8 pk;
        #pragma unroll
        for (int j = 0; j < 8; ++j)
            pk[j] = (short)f2bf(lt[(q*16 + s*8 + j)*65 + px]);
        *(short8*)(dst + s*8) = pk;
    }
}

// ---------------------------------------------------------------------------
// w2 with INLINE fvec (wave-reduced): W2b[b][p][o2][c] bf16 (MFMA A layout)
// v3: store PRE-SWIZZLED (c ^ ((o2&7)<<3)) so dcn_main can stage via
//     global_load_lds with a LINEAR LDS dest and swizzled ds_reads (rule #21:
//     source permutation == read permutation, both the same XOR involution).
// ---------------------------------------------------------------------------
static __device__ __forceinline__ void w2_body(
        int wid, int tid, const float* __restrict__ weight,
        const float* __restrict__ c2w, const float* __restrict__ c1w,
        const float* __restrict__ fea,
        unsigned short* __restrict__ w2b, float* c2s, float* wcol) {
    int o2 = tid & 63, ci = tid >> 6;
    int lane = tid & 63;
    int bp = wid >> 4;
    int c_base = (wid & 15)*4;
    int p = bp % 9, b = bp / 9;
    int c = c_base + ci;

    // inline fvec[b][c] for this wave's c: 4 MAC/lane + wave reduce
    float part = 0.f;
    #pragma unroll
    for (int s = 0; s < 4; ++s)
        part += c1w[c*(4*CIN) + lane + s*64] * fea[b*(4*CIN) + lane + s*64];
    #pragma unroll
    for (int off = 32; off; off >>= 1) part += __shfl_down(part, off);
    float fv = __shfl(part, 0);

    for (int idx = tid; idx < 4096; idx += 256) {
        int o2r = idx >> 6, oc = idx & 63;
        c2s[oc*65 + o2r] = c2w[idx];
    }
    {
        int o = tid & 63, cw = tid >> 6;
        wcol[cw*64 + o] = weight[(o*CIN + (c_base + cw))*9 + p];
    }
    __syncthreads();
    float s = 0.f;
    #pragma unroll 8
    for (int o = 0; o < COUT; ++o) s += c2s[o*65 + o2] * wcol[ci*64 + o];
    // swizzled store (XOR bits 3..5 of c with o2&7) — bijective within row
    w2b[(size_t)bp*4096 + o2*64 + (c ^ ((o2 & 7) << 3))] = f2bf(s * fv);
}

// ---------------------------------------------------------------------------
// conv via LDS im2col tile from fp32 inter (round-7-proven)
// ---------------------------------------------------------------------------
static __device__ __forceinline__ void conv_lds_body(
        int id, int tid, const float* __restrict__ inter,
        const unsigned short* __restrict__ wk2, const float* __restrict__ com_b,
        float* __restrict__ om, float* smemf) {
    unsigned short* til = (unsigned short*)smemf;   // [325][24]
    int bz = id >> 6;
    int b = bz >> 1, mh = bz & 1;
    int by = (id >> 3) & 7, bx = id & 7;
    int x0 = bx*16, y0 = by*16;
    int lane = tid & 63, wv = tid >> 6;
    int nn = lane & 15, qq = lane >> 4;

    f32x4 acc[4];
    #pragma unroll
    for (int nt = 0; nt < 4; ++nt)
        #pragma unroll
        for (int j = 0; j < 4; ++j) acc[nt][j] = 0.f;

    for (int cg = 0; cg < 4; ++cg) {
        __syncthreads();
        const float* I = inter + ((size_t)(b*CIN + cg*16))*HW;
        for (int i = tid; i < 16*324; i += 256) {
            int cl = i / 324, px = i % 324;
            int r = px / 18, cc = px % 18;
            int gy = y0 + r - 1, gx = x0 + cc - 1;
            float v = 0.f;
            if (gy >= 0 && gy < HH && gx >= 0 && gx < WW)
                v = I[(size_t)cl*HW + gy*WW + gx];
            til[px*24 + cl] = f2bf(v);
        }
        if (tid < 24) til[324*24 + tid] = 0;
        __syncthreads();

        short8 afr[5];
        #pragma unroll
        for (int ch = 0; ch < 5; ++ch)
            afr[ch] = *(const short8*)(wk2 +
                (((size_t)(cg*5 + ch)*32 + mh*16 + nn)*32 + qq*8));
        #pragma unroll
        for (int nt = 0; nt < 4; ++nt) {
            int row = wv*4 + nt;
            #pragma unroll
            for (int ch = 0; ch < 5; ++ch) {
                int tap = ch*2 + (qq >> 1);
                int px_idx;
                if (tap > 8) px_idx = 324;
                else {
                    int ky = tap/3, kx = tap%3;
                    px_idx = (row + ky)*18 + (nn + kx);
                }
                short8 bfr = *(const short8*)(til + px_idx*24 + (qq&1)*8);
                acc[nt] = __builtin_amdgcn_mfma_f32_16x16x32_bf16(
                              afr[ch], bfr, acc[nt], 0, 0, 0);
            }
        }
    }

    float* op = om + (size_t)b*27*HW;
    #pragma unroll
    for (int nt = 0; nt < 4; ++nt) {
        int pix = (y0 + wv*4 + nt)*WW + x0 + nn;
        #pragma unroll
        for (int j = 0; j < 4; ++j) {
            int oc = mh*16 + qq*4 + j;
            if (oc < 27)
                op[(size_t)oc*HW + pix] = acc[nt][j] + com_b[oc];
        }
    }
}

// ---------------------------------------------------------------------------
// K2: conv (512) + w2 (576) + fT transpose (1024) = 2112 blocks
// ---------------------------------------------------------------------------
__global__ __launch_bounds__(256) void main2_kernel(
        const float* __restrict__ input_feat,
        const float* __restrict__ inter,
        const unsigned short* __restrict__ wk2,
        const float* __restrict__ com_b,
        const float* __restrict__ weight,
        const float* __restrict__ c2w,
        const float* __restrict__ c1w,
        const float* __restrict__ fea,
        float* __restrict__ om, unsigned short* __restrict__ w2b,
        unsigned short* __restrict__ fT) {
    __shared__ __align__(16) float smem[4416];
    int id = blockIdx.x, tid = threadIdx.x;
    if (id < 512)        conv_lds_body(id, tid, inter, wk2, com_b, om, smem);
    else if (id < 1088)  w2_body(id - 512, tid, weight, c2w, c1w, fea, w2b,
                                 smem, smem + 64*65);
    else                 transpose_body(input_feat, fT, id - 1088, tid, smem);
}

// ---------------------------------------------------------------------------
// K3: main DCN GEMM, bf16 MFMA, split-K across wave pairs.
// v3 (locality theory, spill-free this time):
//  * plain __launch_bounds__(256): v2's (256,8) forced VGPR=32 -> ~170MB of
//    scratch spills (WRITE_SIZE 184MB) and an 85us regression.  Never cap.
//  * A-tile staged via global_load_lds width=16: ZERO staging VGPRs, linear
//    LDS dest; w2b is pre-swizzled by the producer; ds_reads apply the same
//    XOR -> conflict-free (rule #21 satisfied).
//  * XCD batch-binding swizzle: xcd = blk&7, b = xcd>>1.  Per-XCD working set
//    (fT[b] 2MB + om[b] 1.8MB + w2b[b] 72KB) fits the 4MB per-XCD L2.
// ---------------------------------------------------------------------------
__global__ __launch_bounds__(256) void dcn_main_kernel(
        const unsigned short* __restrict__ fT,
        const unsigned short* __restrict__ w2b,
        const float* __restrict__ bias2,
        const float* __restrict__ om,
        float* __restrict__ out) {
    __shared__ __align__(16) unsigned short aT[2][4096];   // 2 x 8KB A-tile
    int id = blockIdx.x;                 // 0..2047
    int xcd = id & 7;                    // round-robin XCD assignment
    int jj  = id >> 3;                   // 0..255 within this XCD
    int b   = xcd >> 1;                  // 2 XCDs per batch -> per-XCD L2 fit
    int y   = jj & 127;
    int xq  = ((xcd & 1) << 1) | (jj >> 7);   // 0..3 (bijective with old grid.x)

    int t = threadIdx.x;
    int lane = t & 63, wv = t >> 6;
    int strip = wv >> 1, kh = wv & 1;
    int nn = lane & 15, qq = lane >> 4;
    int px0 = xq*32 + strip*16;
    int x = px0 + nn;
    int pix = y*WW + x;
    const unsigned short* Fb = fT + (size_t)b*HW*64;
    const float* omb = om + (size_t)b*27*HW;
    const unsigned short* w2src = w2b + (size_t)(b*9)*4096;
    int co = kh*32 + qq*8;

    char* aTc0 = (char*)aT[0];
    char* aTc1 = (char*)aT[1];
    // per-lane staging byte offset within an 8KB tap tile (linear, 2 chunks)
    int stOff = wv*2048 + lane*16;
    // afr (read) addressing: elem byte = (mt*16+nn)*128 + kh*64 + qq*16,
    // XOR row&7 = nn&7 into bits 4..6 -> max 2-way bank aliasing (free)
    int rsw   = (nn & 7) << 4;
    int rbase = kh*64 + qq*16;

    f32x4 acc[4];
    #pragma unroll
    for (int mt = 0; mt < 4; ++mt)
        #pragma unroll
        for (int j = 0; j < 4; ++j)
            acc[mt][j] = kh ? bias2[mt*16 + qq*4 + j] : 0.f;

    // prologue: stage tap 0 A-tile (async, zero VGPRs)
    {
        const char* s = (const char*)w2src;
        __builtin_amdgcn_global_load_lds(
            (const __attribute__((address_space(1))) void*)(s + stOff),
            (__attribute__((address_space(3))) void*)(aTc0 + wv*2048),
            16, 0, 0);
        __builtin_amdgcn_global_load_lds(
            (const __attribute__((address_space(1))) void*)(s + stOff + 1024),
            (__attribute__((address_space(3))) void*)(aTc0 + wv*2048 + 1024),
            16, 0, 0);
    }

    float omy = omb[pix];
    float omx = omb[(size_t)HW + pix];
    float omm = omb[(size_t)18*HW + pix];
    __syncthreads();

    #pragma unroll
    for (int p = 0; p < 9; ++p) {
        char* bufR = (p & 1) ? aTc1 : aTc0;
        char* bufW = (p & 1) ? aTc0 : aTc1;

        // issue next tap's async stage early (hides under gather wait)
        if (p < 8) {
            const char* s = (const char*)(w2src + (size_t)(p + 1)*4096);
            __builtin_amdgcn_global_load_lds(
                (const __attribute__((address_space(1))) void*)(s + stOff),
                (__attribute__((address_space(3))) void*)(bufW + wv*2048),
                16, 0, 0);
            __builtin_amdgcn_global_load_lds(
                (const __attribute__((address_space(1))) void*)(s + stOff + 1024),
                (__attribute__((address_space(3))) void*)(bufW + wv*2048 + 1024),
                16, 0, 0);
        }

        // A-frags for my K-half from LDS (swizzled, conflict-free)
        short8 afr[4];
        #pragma unroll
        for (int mt = 0; mt < 4; ++mt)
            afr[mt] = *(const short8*)(bufR +
                          (((mt*16 + nn)*128 + rbase) ^ rsw));

        // bilinear corner weights for my pixel
        float mv = 1.f / (1.f + expf(-omm));
        float ysv = (float)(y - 1 + p/3) + omy;
        float xsv = (float)(x - 1 + p%3) + omx;
        float y0f = floorf(ysv), x0f = floorf(xsv);
        float ly = ysv - y0f, lx = xsv - x0f;
        int y0 = (int)y0f, x0i = (int)x0f;
        int y1 = y0 + 1, x1 = x0i + 1;
        float vy0 = (y0 >= 0 && y0 < HH) ? 1.f : 0.f;
        float vy1 = (y1 >= 0 && y1 < HH) ? 1.f : 0.f;
        float vx0 = (x0i >= 0 && x0i < WW) ? 1.f : 0.f;
        float vx1 = (x1 >= 0 && x1 < WW) ? 1.f : 0.f;
        float w00 = (1.f-ly)*(1.f-lx)*mv * vy0*vx0;
        float w01 = (1.f-ly)*lx      *mv * vy0*vx1;
        float w10 = ly      *(1.f-lx)*mv * vy1*vx0;
        float w11 = ly      *lx      *mv * vy1*vx1;
        int y0c = min(max(y0,0),HH-1), y1c = min(max(y1,0),HH-1);
        int x0c = min(max(x0i,0),WW-1), x1c = min(max(x1,0),WW-1);
        int i00 = y0c*WW + x0c, i01 = y0c*WW + x1c;
        int i10 = y1c*WW + x0c, i11 = y1c*WW + x1c;

        // prefetch next p's om
        if (p < 8) {
            omy = omb[(size_t)(2*p+2)*HW + pix];
            omx = omb[(size_t)(2*p+3)*HW + pix];
            omm = omb[(size_t)(19+p )*HW + pix];
        }

        // gather my 8 channels' 4 corners (16B each, channel-contiguous)
        short8 c00 = *(const short8*)(Fb + (size_t)i00*64 + co);
        short8 c01 = *(const short8*)(Fb + (size_t)i01*64 + co);
        short8 c10 = *(const short8*)(Fb + (size_t)i10*64 + co);
        short8 c11 = *(const short8*)(Fb + (size_t)i11*64 + co);

        // pack
        unsigned int pw[4];
        #pragma unroll
        for (int jp = 0; jp < 4; ++jp) {
            float v0 = w00*bf2f((unsigned short)c00[2*jp])
                     + w01*bf2f((unsigned short)c01[2*jp])
                     + w10*bf2f((unsigned short)c10[2*jp])
                     + w11*bf2f((unsigned short)c11[2*jp]);
            float v1 = w00*bf2f((unsigned short)c00[2*jp+1])
                     + w01*bf2f((unsigned short)c01[2*jp+1])
                     + w10*bf2f((unsigned short)c10[2*jp+1])
                     + w11*bf2f((unsigned short)c11[2*jp+1]);
            pw[jp] = (unsigned int)f2bf(v0) | ((unsigned int)f2bf(v1) << 16);
        }
        uint4v u4 = {pw[0], pw[1], pw[2], pw[3]};
        short8 bfr = __builtin_bit_cast(short8, u4);

        // MFMA (my K-half only)
        #pragma unroll
        for (int mt = 0; mt < 4; ++mt)
            acc[mt] = __builtin_amdgcn_mfma_f32_16x16x32_bf16(
                          afr[mt], bfr, acc[mt], 0, 0, 0);

        __syncthreads();   // drains vmcnt -> next tap's A-tile is in LDS
    }

    // combine wave-pair partials via LDS (reuse aT[1]: 8KB, free after loop;
    // tap 8 read buffer was aT[0])
    float* red = (float*)aTc1;
    if (kh == 0) {
        #pragma unroll
        for (int mt = 0; mt < 4; ++mt)
            #pragma unroll
            for (int j = 0; j < 4; ++j)
                red[(mt*4 + j)*128 + strip*64 + lane] = acc[mt][j];
    }
    __syncthreads();
    if (kh == 1) {
        float* outp = out + (size_t)b*COUT*HW + (size_t)y*WW + px0 + nn;
        #pragma unroll
        for (int mt = 0; mt < 4; ++mt)
            #pragma unroll
            for (int j = 0; j < 4; ++j)
                outp[(size_t)(mt*16 + qq*4 + j)*HW] =
                    acc[mt][j] + red[(mt*4 + j)*128 + strip*64 + lane];
    }
}

// ---------------------------------------------------------------------------
extern "C" void kernel_launch(void* const* d_in, const int* in_sizes, int n_in,
                              void* d_out, int out_size, void* d_ws, size_t ws_size,
                              hipStream_t stream) {
    const float* input_feat = (const float*)d_in[0];
    const float* inter      = (const float*)d_in[1];
    const float* fea        = (const float*)d_in[2];
    const float* weight     = (const float*)d_in[3];
    const float* bias       = (const float*)d_in[4];
    const float* com_w      = (const float*)d_in[5];
    const float* com_b      = (const float*)d_in[6];
    const float* c1w        = (const float*)d_in[7];
    const float* c2w        = (const float*)d_in[8];
    float* out = (float*)d_out;

    float* ws    = (float*)d_ws;
    float* bias2 = ws + 256;                               // 64 (in pad area)
    unsigned short* w2b = (unsigned short*)(ws + 512);     // 147456 us
    float* om    = ws + 512 + 73728;                       // 1769472 f
    unsigned short* wk2 = (unsigned short*)(om + 1769472); // 20480 us
    unsigned short* fT  = wk2 + 20480;                     // 4194304 us

    prep_kernel<<<81, 256, 0, stream>>>(com_w, c2w, bias, wk2, bias2);
    main2_kernel<<<2112, 256, 0, stream>>>(input_feat, inter, wk2, com_b,
                                           weight, c2w, c1w, fea, om, w2b, fT);
    dcn_main_kernel<<<2048, 256, 0, stream>>>(fT, w2b, bias2, om, out);
}

// Round 4
// 151.364 us; speedup vs baseline: 1.3713x; 1.1258x over previous
//
#include <hip/hip_runtime.h>
#include <math.h>

// Problem constants
#define BB 4
#define CIN 64
#define COUT 64
#define HH 128
#define WW 128
#define HW (HH*WW)

typedef __attribute__((ext_vector_type(8))) short short8;   // 8 bf16 = 4 VGPRs
typedef __attribute__((ext_vector_type(4))) float f32x4;
typedef __attribute__((ext_vector_type(4))) unsigned int uint4v;

static __device__ __forceinline__ unsigned short f2bf(float f) {
    unsigned int u = __builtin_bit_cast(unsigned int, f);
    u += 0x7fffu + ((u >> 16) & 1u);          // round-to-nearest-even
    return (unsigned short)(u >> 16);
}
static __device__ __forceinline__ float bf2f(unsigned short h) {
    unsigned int u = ((unsigned int)h) << 16;
    return __builtin_bit_cast(float, u);
}

// ---------------------------------------------------------------------------
// K1: wkpack (80 blocks) + bias2 (1 block).  Tiny; everything else moved out.
// ---------------------------------------------------------------------------
__global__ __launch_bounds__(256) void prep_kernel(
        const float* __restrict__ com_w, const float* __restrict__ c2w,
        const float* __restrict__ bias,
        unsigned short* __restrict__ wk2, float* __restrict__ bias2) {
    int id = blockIdx.x, tid = threadIdx.x;
    if (id < 80) {
        int i = id*256 + tid;               // < 20480
        int k = i & 31, oc = (i >> 5) & 31;
        int cc5 = i >> 10;                  // cg*5 + chunk
        int cg = cc5 / 5, ch = cc5 % 5;
        int tap = ch*2 + (k >> 4);
        int c = cg*16 + (k & 15);
        float v = 0.f;
        if (tap < 9 && oc < 27) v = com_w[((size_t)oc*64 + c)*9 + tap];
        wk2[i] = f2bf(v);
    } else if (tid < COUT) {
        float s2 = 0.f;
        for (int o = 0; o < COUT; ++o) s2 += c2w[tid*COUT + o] * bias[o];
        bias2[tid] = s2;
    }
}

// ---------------------------------------------------------------------------
// channel-last bf16 transpose of one (b, 64-px strip): src[b][c][px]->dst[b][px][c]
// ---------------------------------------------------------------------------
static __device__ __forceinline__ void transpose_body(
        const float* __restrict__ srcb, unsigned short* __restrict__ dstb,
        int tb, int tid, float* lt /* 64*65 floats */) {
    int b = tb >> 8;
    int px0 = (tb & 255) * 64;
    const float* src = srcb + (size_t)b*CIN*HW + px0;
    for (int i = tid; i < 4096; i += 256) {
        int c = i >> 6, px = i & 63;
        lt[c*65 + px] = src[(size_t)c*HW + px];
    }
    __syncthreads();
    int q = tid & 3, px = tid >> 2;
    unsigned short* dst = dstb + ((size_t)b*HW + px0 + px)*64 + q*16;
    #pragma unroll
    for (int s = 0; s < 2; ++s) {
        short8 pk;
        #pragma unroll
        for (int j = 0; j < 8; ++j)
            pk[j] = (short)f2bf(lt[(q*16 + s*8 + j)*65 + px]);
        *(short8*)(dst + s*8) = pk;
    }
}

// ---------------------------------------------------------------------------
// w2 with INLINE fvec (wave-reduced): W2b[b][p][o2][c] bf16 (MFMA A layout)
// Stores PRE-SWIZZLED (c ^ ((o2&7)<<3)) so dcn_main can stage via
// global_load_lds with a LINEAR LDS dest and swizzled ds_reads (rule #21).
// ---------------------------------------------------------------------------
static __device__ __forceinline__ void w2_body(
        int wid, int tid, const float* __restrict__ weight,
        const float* __restrict__ c2w, const float* __restrict__ c1w,
        const float* __restrict__ fea,
        unsigned short* __restrict__ w2b, float* c2s, float* wcol) {
    int o2 = tid & 63, ci = tid >> 6;
    int lane = tid & 63;
    int bp = wid >> 4;
    int c_base = (wid & 15)*4;
    int p = bp % 9, b = bp / 9;
    int c = c_base + ci;

    // inline fvec[b][c] for this wave's c: 4 MAC/lane + wave reduce
    float part = 0.f;
    #pragma unroll
    for (int s = 0; s < 4; ++s)
        part += c1w[c*(4*CIN) + lane + s*64] * fea[b*(4*CIN) + lane + s*64];
    #pragma unroll
    for (int off = 32; off; off >>= 1) part += __shfl_down(part, off);
    float fv = __shfl(part, 0);

    for (int idx = tid; idx < 4096; idx += 256) {
        int o2r = idx >> 6, oc = idx & 63;
        c2s[oc*65 + o2r] = c2w[idx];
    }
    {
        int o = tid & 63, cw = tid >> 6;
        wcol[cw*64 + o] = weight[(o*CIN + (c_base + cw))*9 + p];
    }
    __syncthreads();
    float s = 0.f;
    #pragma unroll 8
    for (int o = 0; o < COUT; ++o) s += c2s[o*65 + o2] * wcol[ci*64 + o];
    // swizzled store (XOR bits 3..5 of c with o2&7) — bijective within row
    w2b[(size_t)bp*4096 + o2*64 + (c ^ ((o2 & 7) << 3))] = f2bf(s * fv);
}

// ---------------------------------------------------------------------------
// conv v2: 512 blocks = b(4) x by(16) x bx(8); tile = 8 rows x 16 px, ALL 27
// output channels per block (mh merged -> B-tile staged ONCE, each ds_read
// feeds 2 MFMAs).  Staging is division-free: thread owns fixed (cl,cc), loops
// 10 rows with constant offsets; branch-free clamp+mask (loads always
// in-bounds).  Numerics identical to v1 (same accumulation order per oc).
// ---------------------------------------------------------------------------
static __device__ __forceinline__ void conv_lds_body(
        int id, int tid, const float* __restrict__ inter,
        const unsigned short* __restrict__ wk2, const float* __restrict__ com_b,
        float* __restrict__ om, float* smemf) {
    unsigned short* til = (unsigned short*)smemf;   // [182][24] shorts (8736B)
    int b  = id >> 7;          // 0..3
    int t7 = id & 127;
    int by = t7 >> 3;          // 0..15
    int bx = t7 & 7;           // 0..7
    int x0 = bx*16, y0 = by*8;
    int lane = tid & 63, wv = tid >> 6;
    int nn = lane & 15, qq = lane >> 4;

    // zero the dummy px row (180) once; staging never overwrites it
    if (tid < 24) til[180*24 + tid] = 0;

    // staging coords fixed per thread: cl = tid&15, cc = tid>>4 (0..15)
    int scl = tid & 15, scc = tid >> 4;
    int sgx  = x0 + scc - 1;
    int sgxc = max(sgx, 0);                 // <= 126, always in-bounds
    float sfx = ((unsigned)sgx < WW) ? 1.f : 0.f;

    f32x4 acc[2][2];
    #pragma unroll
    for (int nt = 0; nt < 2; ++nt)
        #pragma unroll
        for (int mh = 0; mh < 2; ++mh)
            #pragma unroll
            for (int j = 0; j < 4; ++j) acc[nt][mh][j] = 0.f;

    for (int cg = 0; cg < 4; ++cg) {
        __syncthreads();                    // previous cg's reads done
        const float* I = inter + ((size_t)(b*CIN + cg*16))*HW;

        // main staging: rows r=0..9, cc=0..15 (2560 elems, 10/thread)
        {
            const float* colp = I + (size_t)scl*HW + sgxc;
            unsigned short* tp = til + scc*24 + scl;
            #pragma unroll
            for (int r = 0; r < 10; ++r) {
                int gy  = y0 + r - 1;
                int gyc = min(max(gy, 0), HH-1);
                float m = ((unsigned)gy < HH) ? sfx : 0.f;
                float v = colp[(size_t)gyc*WW] * m;
                tp[r*(18*24)] = f2bf(v);
            }
        }
        // tail staging: cc=16,17 (320 elems), i = r*32 + ccb*16 + cl
        #pragma unroll
        for (int k = 0; k < 2; ++k) {
            int i = k*256 + tid;
            if (i < 320) {
                int cl  = i & 15;
                int ccb = (i >> 4) & 1;         // cc = 16+ccb
                int r   = i >> 5;               // 0..9
                int gx  = x0 + 15 + ccb;
                int gy  = y0 + r - 1;
                int gxc = min(gx, WW-1);
                int gyc = min(max(gy, 0), HH-1);
                float m = (((unsigned)gy < HH) && ((unsigned)gx < WW)) ? 1.f : 0.f;
                float v = I[(size_t)cl*HW + gyc*WW + gxc] * m;
                til[(r*18 + 16 + ccb)*24 + cl] = f2bf(v);
            }
        }
        __syncthreads();

        #pragma unroll
        for (int ch = 0; ch < 5; ++ch) {
            short8 a0 = *(const short8*)(wk2 +
                (((size_t)(cg*5 + ch)*32 + nn)*32 + qq*8));
            short8 a1 = *(const short8*)(wk2 +
                (((size_t)(cg*5 + ch)*32 + 16 + nn)*32 + qq*8));
            int tap = ch*2 + (qq >> 1);
            #pragma unroll
            for (int nt = 0; nt < 2; ++nt) {
                int row = wv*2 + nt;            // 0..7
                int px_idx;
                if (tap > 8) px_idx = 180;
                else {
                    int ky = tap/3, kx = tap%3;
                    px_idx = (row + ky)*18 + (nn + kx);
                }
                short8 bfr = *(const short8*)(til + px_idx*24 + (qq&1)*8);
                acc[nt][0] = __builtin_amdgcn_mfma_f32_16x16x32_bf16(
                                 a0, bfr, acc[nt][0], 0, 0, 0);
                acc[nt][1] = __builtin_amdgcn_mfma_f32_16x16x32_bf16(
                                 a1, bfr, acc[nt][1], 0, 0, 0);
            }
        }
    }

    float* op = om + (size_t)b*27*HW;
    #pragma unroll
    for (int nt = 0; nt < 2; ++nt) {
        int pix = (y0 + wv*2 + nt)*WW + x0 + nn;
        #pragma unroll
        for (int mh = 0; mh < 2; ++mh)
            #pragma unroll
            for (int j = 0; j < 4; ++j) {
                int oc = mh*16 + qq*4 + j;
                if (oc < 27)
                    op[(size_t)oc*HW + pix] = acc[nt][mh][j] + com_b[oc];
            }
    }
}

// ---------------------------------------------------------------------------
// K2: conv (512) + w2 (576) + fT transpose (1024) = 2112 blocks
// ---------------------------------------------------------------------------
__global__ __launch_bounds__(256) void main2_kernel(
        const float* __restrict__ input_feat,
        const float* __restrict__ inter,
        const unsigned short* __restrict__ wk2,
        const float* __restrict__ com_b,
        const float* __restrict__ weight,
        const float* __restrict__ c2w,
        const float* __restrict__ c1w,
        const float* __restrict__ fea,
        float* __restrict__ om, unsigned short* __restrict__ w2b,
        unsigned short* __restrict__ fT) {
    __shared__ __align__(16) float smem[4416];
    int id = blockIdx.x, tid = threadIdx.x;
    if (id < 512)        conv_lds_body(id, tid, inter, wk2, com_b, om, smem);
    else if (id < 1088)  w2_body(id - 512, tid, weight, c2w, c1w, fea, w2b,
                                 smem, smem + 64*65);
    else                 transpose_body(input_feat, fT, id - 1088, tid, smem);
}

// ---------------------------------------------------------------------------
// K3: main DCN GEMM, bf16 MFMA, split-K across wave pairs.  (round-3-proven)
//  * A-tile staged via global_load_lds width=16 (zero staging VGPRs); w2b is
//    pre-swizzled by the producer; ds_reads apply the same XOR (rule #21).
//  * XCD batch-binding swizzle: per-XCD working set fits the 4MB L2.
// ---------------------------------------------------------------------------
__global__ __launch_bounds__(256) void dcn_main_kernel(
        const unsigned short* __restrict__ fT,
        const unsigned short* __restrict__ w2b,
        const float* __restrict__ bias2,
        const float* __restrict__ om,
        float* __restrict__ out) {
    __shared__ __align__(16) unsigned short aT[2][4096];   // 2 x 8KB A-tile
    int id = blockIdx.x;                 // 0..2047
    int xcd = id & 7;                    // round-robin XCD assignment
    int jj  = id >> 3;                   // 0..255 within this XCD
    int b   = xcd >> 1;                  // 2 XCDs per batch -> per-XCD L2 fit
    int y   = jj & 127;
    int xq  = ((xcd & 1) << 1) | (jj >> 7);   // 0..3 (bijective with old grid.x)

    int t = threadIdx.x;
    int lane = t & 63, wv = t >> 6;
    int strip = wv >> 1, kh = wv & 1;
    int nn = lane & 15, qq = lane >> 4;
    int px0 = xq*32 + strip*16;
    int x = px0 + nn;
    int pix = y*WW + x;
    const unsigned short* Fb = fT + (size_t)b*HW*64;
    const float* omb = om + (size_t)b*27*HW;
    const unsigned short* w2src = w2b + (size_t)(b*9)*4096;
    int co = kh*32 + qq*8;

    char* aTc0 = (char*)aT[0];
    char* aTc1 = (char*)aT[1];
    // per-lane staging byte offset within an 8KB tap tile (linear, 2 chunks)
    int stOff = wv*2048 + lane*16;
    // afr (read) addressing: elem byte = (mt*16+nn)*128 + kh*64 + qq*16,
    // XOR row&7 = nn&7 into bits 4..6 -> max 2-way bank aliasing (free)
    int rsw   = (nn & 7) << 4;
    int rbase = kh*64 + qq*16;

    f32x4 acc[4];
    #pragma unroll
    for (int mt = 0; mt < 4; ++mt)
        #pragma unroll
        for (int j = 0; j < 4; ++j)
            acc[mt][j] = kh ? bias2[mt*16 + qq*4 + j] : 0.f;

    // prologue: stage tap 0 A-tile (async, zero VGPRs)
    {
        const char* s = (const char*)w2src;
        __builtin_amdgcn_global_load_lds(
            (const __attribute__((address_space(1))) void*)(s + stOff),
            (__attribute__((address_space(3))) void*)(aTc0 + wv*2048),
            16, 0, 0);
        __builtin_amdgcn_global_load_lds(
            (const __attribute__((address_space(1))) void*)(s + stOff + 1024),
            (__attribute__((address_space(3))) void*)(aTc0 + wv*2048 + 1024),
            16, 0, 0);
    }

    float omy = omb[pix];
    float omx = omb[(size_t)HW + pix];
    float omm = omb[(size_t)18*HW + pix];
    __syncthreads();

    #pragma unroll
    for (int p = 0; p < 9; ++p) {
        char* bufR = (p & 1) ? aTc1 : aTc0;
        char* bufW = (p & 1) ? aTc0 : aTc1;

        // issue next tap's async stage early (hides under gather wait)
        if (p < 8) {
            const char* s = (const char*)(w2src + (size_t)(p + 1)*4096);
            __builtin_amdgcn_global_load_lds(
                (const __attribute__((address_space(1))) void*)(s + stOff),
                (__attribute__((address_space(3))) void*)(bufW + wv*2048),
                16, 0, 0);
            __builtin_amdgcn_global_load_lds(
                (const __attribute__((address_space(1))) void*)(s + stOff + 1024),
                (__attribute__((address_space(3))) void*)(bufW + wv*2048 + 1024),
                16, 0, 0);
        }

        // A-frags for my K-half from LDS (swizzled, conflict-free)
        short8 afr[4];
        #pragma unroll
        for (int mt = 0; mt < 4; ++mt)
            afr[mt] = *(const short8*)(bufR +
                          (((mt*16 + nn)*128 + rbase) ^ rsw));

        // bilinear corner weights for my pixel
        float mv = 1.f / (1.f + expf(-omm));
        float ysv = (float)(y - 1 + p/3) + omy;
        float xsv = (float)(x - 1 + p%3) + omx;
        float y0f = floorf(ysv), x0f = floorf(xsv);
        float ly = ysv - y0f, lx = xsv - x0f;
        int y0 = (int)y0f, x0i = (int)x0f;
        int y1 = y0 + 1, x1 = x0i + 1;
        float vy0 = (y0 >= 0 && y0 < HH) ? 1.f : 0.f;
        float vy1 = (y1 >= 0 && y1 < HH) ? 1.f : 0.f;
        float vx0 = (x0i >= 0 && x0i < WW) ? 1.f : 0.f;
        float vx1 = (x1 >= 0 && x1 < WW) ? 1.f : 0.f;
        float w00 = (1.f-ly)*(1.f-lx)*mv * vy0*vx0;
        float w01 = (1.f-ly)*lx      *mv * vy0*vx1;
        float w10 = ly      *(1.f-lx)*mv * vy1*vx0;
        float w11 = ly      *lx      *mv * vy1*vx1;
        int y0c = min(max(y0,0),HH-1), y1c = min(max(y1,0),HH-1);
        int x0c = min(max(x0i,0),WW-1), x1c = min(max(x1,0),WW-1);
        int i00 = y0c*WW + x0c, i01 = y0c*WW + x1c;
        int i10 = y1c*WW + x0c, i11 = y1c*WW + x1c;

        // prefetch next p's om
        if (p < 8) {
            omy = omb[(size_t)(2*p+2)*HW + pix];
            omx = omb[(size_t)(2*p+3)*HW + pix];
            omm = omb[(size_t)(19+p )*HW + pix];
        }

        // gather my 8 channels' 4 corners (16B each, channel-contiguous)
        short8 c00 = *(const short8*)(Fb + (size_t)i00*64 + co);
        short8 c01 = *(const short8*)(Fb + (size_t)i01*64 + co);
        short8 c10 = *(const short8*)(Fb + (size_t)i10*64 + co);
        short8 c11 = *(const short8*)(Fb + (size_t)i11*64 + co);

        // pack
        unsigned int pw[4];
        #pragma unroll
        for (int jp = 0; jp < 4; ++jp) {
            float v0 = w00*bf2f((unsigned short)c00[2*jp])
                     + w01*bf2f((unsigned short)c01[2*jp])
                     + w10*bf2f((unsigned short)c10[2*jp])
                     + w11*bf2f((unsigned short)c11[2*jp]);
            float v1 = w00*bf2f((unsigned short)c00[2*jp+1])
                     + w01*bf2f((unsigned short)c01[2*jp+1])
                     + w10*bf2f((unsigned short)c10[2*jp+1])
                     + w11*bf2f((unsigned short)c11[2*jp+1]);
            pw[jp] = (unsigned int)f2bf(v0) | ((unsigned int)f2bf(v1) << 16);
        }
        uint4v u4 = {pw[0], pw[1], pw[2], pw[3]};
        short8 bfr = __builtin_bit_cast(short8, u4);

        // MFMA (my K-half only)
        #pragma unroll
        for (int mt = 0; mt < 4; ++mt)
            acc[mt] = __builtin_amdgcn_mfma_f32_16x16x32_bf16(
                          afr[mt], bfr, acc[mt], 0, 0, 0);

        __syncthreads();   // drains vmcnt -> next tap's A-tile is in LDS
    }

    // combine wave-pair partials via LDS (reuse aT[1]: 8KB, free after loop;
    // tap 8 read buffer was aT[0])
    float* red = (float*)aTc1;
    if (kh == 0) {
        #pragma unroll
        for (int mt = 0; mt < 4; ++mt)
            #pragma unroll
            for (int j = 0; j < 4; ++j)
                red[(mt*4 + j)*128 + strip*64 + lane] = acc[mt][j];
    }
    __syncthreads();
    if (kh == 1) {
        float* outp = out + (size_t)b*COUT*HW + (size_t)y*WW + px0 + nn;
        #pragma unroll
        for (int mt = 0; mt < 4; ++mt)
            #pragma unroll
            for (int j = 0; j < 4; ++j)
                outp[(size_t)(mt*16 + qq*4 + j)*HW] =
                    acc[mt][j] + red[(mt*4 + j)*128 + strip*64 + lane];
    }
}

// ---------------------------------------------------------------------------
extern "C" void kernel_launch(void* const* d_in, const int* in_sizes, int n_in,
                              void* d_out, int out_size, void* d_ws, size_t ws_size,
                              hipStream_t stream) {
    const float* input_feat = (const float*)d_in[0];
    const float* inter      = (const float*)d_in[1];
    const float* fea        = (const float*)d_in[2];
    const float* weight     = (const float*)d_in[3];
    const float* bias       = (const float*)d_in[4];
    const float* com_w      = (const float*)d_in[5];
    const float* com_b      = (const float*)d_in[6];
    const float* c1w        = (const float*)d_in[7];
    const float* c2w        = (const float*)d_in[8];
    float* out = (float*)d_out;

    float* ws    = (float*)d_ws;
    float* bias2 = ws + 256;                               // 64 (in pad area)
    unsigned short* w2b = (unsigned short*)(ws + 512);     // 147456 us
    float* om    = ws + 512 + 73728;                       // 1769472 f
    unsigned short* wk2 = (unsigned short*)(om + 1769472); // 20480 us
    unsigned short* fT  = wk2 + 20480;                     // 4194304 us

    prep_kernel<<<81, 256, 0, stream>>>(com_w, c2w, bias, wk2, bias2);
    main2_kernel<<<2112, 256, 0, stream>>>(input_feat, inter, wk2, com_b,
                                           weight, c2w, c1w, fea, om, w2b, fT);
    dcn_main_kernel<<<2048, 256, 0, stream>>>(fT, w2b, bias2, om, out);
}